// Round 11
// baseline (108.919 us; speedup 1.0000x reference)
//
#include <hip/hip_runtime.h>
#include <hip/hip_bf16.h>

#define B_   8
#define SQ_  2048
#define SK_  2048
#define D_   128
#define GRID 256

typedef __attribute__((ext_vector_type(8))) _Float16 f16x8;
typedef __attribute__((ext_vector_type(4))) _Float16 f16x4;
typedef __attribute__((ext_vector_type(4))) float    f32x4;

// Fragment-major layouts (f16), lane l, hi = l>>4, ql = l&15:
//  Qf[b][qt:128][ks:4][l][8] : elem (q = qt*16+ql, d = ks*32+hi*8+j)  PRE-SCALED log2e/8
//  Kf[b][kt:128][ks:4][l][8] : elem (k = kt*16+ql, d = ks*32+hi*8+j)  PRE-SCALED 1/16
//  Vf[b][kt:64][dt:8][l][8]  : elem (k = kt*32+hi*8+j, d = dt*16+ql)   (B-frag for PV)
//  Pf[b][qtl:128][kt:64][l][8]: elem (q = qtl*16+ql, k = kt*32+hi*8+j) (A-frag for PV)
#define QK_BSTRIDE (128 * 4 * 64 * 8)           // 262144 elems per batch
#define VF_BSTRIDE (64 * 8 * 64 * 8)            // 262144 elems per batch
#define P_BSTRIDE  ((size_t)128 * 64 * 512)     // 4194304 elems per batch

__device__ __forceinline__ void dma16(const void* g, void* l) {
    __builtin_amdgcn_global_load_lds(
        (const __attribute__((address_space(1))) unsigned int*)g,
        (__attribute__((address_space(3))) unsigned int*)l, 16, 0, 0);
}

__device__ __forceinline__ float fast_exp2(float x) {
#if __has_builtin(__builtin_amdgcn_exp2f)
    return __builtin_amdgcn_exp2f(x);
#else
    return __expf(x * 0.6931471805599453f);
#endif
}

// Device-scope sense-reversing barrier. bar[0] = counter, bar[32] = generation.
// Timeout valve: if co-residency ever fails, produce wrong answers (bench
// fails loudly) instead of hanging.
__device__ __forceinline__ void gbar(unsigned* bar) {
    __syncthreads();
    if (threadIdx.x == 0) {
        unsigned* ctr = bar;
        unsigned* gen = bar + 32;
        unsigned g = __hip_atomic_load(gen, __ATOMIC_RELAXED, __HIP_MEMORY_SCOPE_AGENT);
        unsigned a = __hip_atomic_fetch_add(ctr, 1u, __ATOMIC_ACQ_REL, __HIP_MEMORY_SCOPE_AGENT);
        if (a == GRID - 1) {
            __hip_atomic_store(ctr, 0u, __ATOMIC_RELAXED, __HIP_MEMORY_SCOPE_AGENT);
            __hip_atomic_store(gen, g + 1u, __ATOMIC_RELEASE, __HIP_MEMORY_SCOPE_AGENT);
        } else {
            long long t0 = clock64();
            while (__hip_atomic_load(gen, __ATOMIC_ACQUIRE, __HIP_MEMORY_SCOPE_AGENT) == g) {
                __builtin_amdgcn_s_sleep(32);
                if (clock64() - t0 > 2000000000LL) break;   // never hit when co-resident
            }
        }
    }
    __syncthreads();
}

// ---------------------------------------------------------------------------
// Persistent mega-kernel: {prep | zred | av} with 2 device barriers.
// grid 256 (1 block/CU via 96KB LDS), block 512 (8 waves).
// ---------------------------------------------------------------------------
__global__ __launch_bounds__(512)
void mega(const float* __restrict__ Q, const float* __restrict__ K,
          const float* __restrict__ V,
          _Float16* __restrict__ Qf, _Float16* __restrict__ Kf,
          _Float16* __restrict__ Vf, _Float16* __restrict__ Pf,
          unsigned* __restrict__ bar, float* __restrict__ out) {
    __shared__ __attribute__((aligned(16))) char smem[98304];   // 96 KB union

    const int bid = blockIdx.x;
    const int t   = threadIdx.x;
    const int w   = t >> 6;
    const int l   = t & 63;
    const int hi  = l >> 4, ql = l & 15;

    // ================= Phase P: operand prep (512 units, 2/block) =========
    {
        _Float16 (*T)[136] = (_Float16 (*)[136])smem;   // QK: [128][136], V: [64][136]
#pragma unroll 1
        for (int u = bid; u < 512; u += GRID) {
            if (u < 256) {
                // ---- Q/K 128-row unit: coalesced read -> LDS -> frag store
                const int   tens = u >> 7;               // 0 = Q, 1 = K
                const float* src = tens ? K : Q;
                _Float16*    dst = tens ? Kf : Qf;
                const float  sc  = tens ? 0.0625f : 0.18033688f;  // 1/16, log2e/8
                const int b  = (u >> 4) & 7;
                const int rb = u & 15;                   // 128-row block
                const int row = t >> 2, c0 = (t & 3) * 32;
                const float* srow = src + ((size_t)b * SQ_ + rb * 128 + row) * D_ + c0;
#pragma unroll
                for (int j = 0; j < 32; j += 4) {
                    f32x4 v = *(const f32x4*)(srow + j);
                    f16x4 h;
                    h[0] = (_Float16)(v[0] * sc); h[1] = (_Float16)(v[1] * sc);
                    h[2] = (_Float16)(v[2] * sc); h[3] = (_Float16)(v[3] * sc);
                    *(f16x4*)&T[row][c0 + j] = h;
                }
                __syncthreads();
#pragma unroll
                for (int it = 0; it < 4; ++it) {
                    int c  = it * 512 + t;               // 0..2047
                    int ll = c & 63;
                    int ks = (c >> 6) & 3;
                    int qt = c >> 8;                     // 0..7
                    f16x8 r = *(const f16x8*)&T[qt * 16 + (ll & 15)][ks * 32 + (ll >> 4) * 8];
                    *(f16x8*)(dst + ((((size_t)b * 128 + rb * 8 + qt) * 4 + ks) * 64 + ll) * 8) = r;
                }
            } else {
                // ---- V 64-row unit: coalesced read -> LDS -> transposed frags
                const int vu = u - 256;                  // 0..255
                const int b  = vu >> 5;
                const int kb = vu & 31;                  // 64-k block
                const int row = t >> 3, c0 = (t & 7) * 16;
                const float* srow = V + ((size_t)b * SK_ + kb * 64 + row) * D_ + c0;
#pragma unroll
                for (int j = 0; j < 16; j += 4) {
                    f32x4 v = *(const f32x4*)(srow + j);
                    f16x4 h;
                    h[0] = (_Float16)v[0]; h[1] = (_Float16)v[1];
                    h[2] = (_Float16)v[2]; h[3] = (_Float16)v[3];
                    *(f16x4*)&T[row][c0 + j] = h;
                }
                __syncthreads();
#pragma unroll
                for (int it = 0; it < 2; ++it) {
                    int s   = it * 512 + t;              // 0..1023
                    int ll  = s & 63;
                    int dt  = (s >> 6) & 7;
                    int ktl = s >> 9;                    // 0..1
                    int lhi = ll >> 4, lql = ll & 15;
                    f16x8 r;
#pragma unroll
                    for (int j = 0; j < 8; ++j) r[j] = T[ktl * 32 + lhi * 8 + j][dt * 16 + lql];
                    *(f16x8*)(Vf + (((size_t)b * 64 + kb * 2 + ktl) * 8 + dt) * 512 + (size_t)ll * 8) = r;
                }
            }
            __syncthreads();                             // T reuse guard
        }
    }
    gbar(bar);

    // ================= Phase Z: P_b = exp2(S_b)/sum_b (4 units/block) ======
    {
        _Float16* E  = (_Float16*)smem;                  // [8][64][64] = 64 KB
        f16x4*    E4 = (f16x4*)smem;
        const f16x8* E8 = (const f16x8*)smem;
        const _Float16* Qb = Qf + (size_t)w * QK_BSTRIDE;   // wave = batch
        const _Float16* Kb = Kf + (size_t)w * QK_BSTRIDE;
#pragma unroll 1
        for (int i = 0; i < 4; ++i) {
            const int z     = bid * 4 + i;               // unit id 0..1023
            const int qtile = z >> 5;
            const int ktile = z & 31;                    // XCD-pinned k-slice

            // swapped S^T = mfma(K, Q): lane holds k = kk*16+hi*4+r, q = qq*16+ql
            f32x4 s[4][4] = {};
            __builtin_amdgcn_s_setprio(1);
#pragma unroll
            for (int ks = 0; ks < 4; ++ks) {
                f16x8 kf[4];
#pragma unroll
                for (int kk = 0; kk < 4; ++kk)
                    kf[kk] = *(const f16x8*)(Kb + ((((size_t)ktile * 4 + kk) * 4 + ks) * 64 + l) * 8);
#pragma unroll
                for (int qq = 0; qq < 4; ++qq) {
                    f16x8 qv = *(const f16x8*)(Qb + ((((size_t)qtile * 4 + qq) * 4 + ks) * 64 + l) * 8);
#pragma unroll
                    for (int kk = 0; kk < 4; ++kk)
                        s[kk][qq] = __builtin_amdgcn_mfma_f32_16x16x32_f16(kf[kk], qv, s[kk][qq], 0, 0, 0);
                }
            }
            __builtin_amdgcn_s_setprio(0);

            // E[b][q][k] = exp2(S), 16B-granule XOR swizzle on k-group
#pragma unroll
            for (int kk = 0; kk < 4; ++kk)
#pragma unroll
                for (int qq = 0; qq < 4; ++qq) {
                    f16x4 e;
#pragma unroll
                    for (int r = 0; r < 4; ++r)
                        e[r] = (_Float16)fast_exp2(s[kk][qq][r]);
                    int q = qq * 16 + ql;
                    int k = kk * 16 + hi * 4;
                    int g16 = ((w * 64 + q) << 3) + ((k >> 3) ^ (q & 7));
                    E4[g16 * 2 + ((k >> 2) & 1)] = e;
                }
            __syncthreads();

            // thread -> PV-A-frag slot; reduce 8 batches; write P for all 8
            const int ktl  = t >> 8;                     // 0..1
            const int qq2  = (t >> 6) & 3;
            const int l2   = t & 63;
            const int q_loc  = qq2 * 16 + (l2 & 15);
            const int k0_loc = ktl * 32 + (l2 >> 4) * 8;
            const int eidx   = (q_loc << 3) + ((k0_loc >> 3) ^ (q_loc & 7));

            f16x8 zsum = E8[eidx];
#pragma unroll
            for (int bb = 1; bb < 8; ++bb) zsum = zsum + E8[bb * 512 + eidx];
            float inv[8];
#pragma unroll
            for (int j = 0; j < 8; ++j) inv[j] = __builtin_amdgcn_rcpf((float)zsum[j]);

            const size_t pbase = (((size_t)(qtile * 4 + qq2)) * 64 + (ktile * 2 + ktl)) * 512
                               + (size_t)l2 * 8;
#pragma unroll
            for (int bb = 0; bb < 8; ++bb) {
                f16x8 e = E8[bb * 512 + eidx];
                f16x8 p;
#pragma unroll
                for (int j = 0; j < 8; ++j) p[j] = (_Float16)((float)e[j] * inv[j]);
                *(f16x8*)(Pf + (size_t)bb * P_BSTRIDE + pbase) = p;
            }
            __syncthreads();                             // E reuse guard
        }
    }
    gbar(bar);

    // ================= Phase A: O_b = P_b @ V_b (1 unit/block) =============
    {
        _Float16* lds = (_Float16*)smem;                 // 4 x 24 KB quad-buffer
        const int b  = bid & 7;                          // batch -> XCD pinned
        const int mt = bid >> 3;                         // 64-q M-tile
        const int wq = w >> 2;                           // 0..1
        const int wd = w & 3;                            // 0..3

        const _Float16* Pb = Pf + (size_t)b * P_BSTRIDE;
        const _Float16* Vb = Vf + (size_t)b * VF_BSTRIDE;

#define STAGE(bufi, kt2) do {                                                  \
    _Float16* dst0 = lds + (size_t)(bufi) * 12288;                             \
    _Pragma("unroll")                                                          \
    for (int u = 0; u < 3; ++u) {                                              \
        int c = w * 3 + u;                                                     \
        const _Float16* srcp;                                                  \
        if (c < 8)                                                             \
            srcp = Pb + (((size_t)(mt * 4 + (c >> 1))) * 64 + ((kt2) * 2 + (c & 1))) * 512 + (size_t)l * 8; \
        else {                                                                 \
            int cv = c - 8;                                                    \
            srcp = Vb + (((size_t)((kt2) * 2 + (cv >> 3))) * 8 + (cv & 7)) * 512 + (size_t)l * 8; \
        }                                                                      \
        dma16(srcp, dst0 + c * 512);                                           \
    }                                                                          \
} while (0)

#define MFMA_PHASE(bufi) do {                                                  \
    const _Float16* Bf = lds + (size_t)(bufi) * 12288;                         \
    _Pragma("unroll")                                                          \
    for (int ktl = 0; ktl < 2; ++ktl) {                                        \
        f16x8 pfr[2], vfr[2];                                                  \
        _Pragma("unroll")                                                      \
        for (int i = 0; i < 2; ++i)                                            \
            pfr[i] = *(const f16x8*)(Bf + ((wq * 2 + i) * 2 + ktl) * 512 + l * 8); \
        _Pragma("unroll")                                                      \
        for (int j = 0; j < 2; ++j)                                            \
            vfr[j] = *(const f16x8*)(Bf + 4096 + (ktl * 8 + wd * 2 + j) * 512 + l * 8); \
        _Pragma("unroll")                                                      \
        for (int i = 0; i < 2; ++i)                                            \
            _Pragma("unroll")                                                  \
            for (int j = 0; j < 2; ++j)                                        \
                acc[i][j] = __builtin_amdgcn_mfma_f32_16x16x32_f16(pfr[i], vfr[j], acc[i][j], 0, 0, 0); \
    }                                                                          \
} while (0)

        f32x4 acc[2][2] = {};
        STAGE(0, 0);
        STAGE(1, 1);
        STAGE(2, 2);
        for (int kt2 = 0; kt2 < 32; ++kt2) {
            // oldest in-flight group = stage[kt2]; stale Z-phase stores only
            // precede it in FIFO order, so counted waits remain safe.
            if (kt2 <= 29)      asm volatile("s_waitcnt vmcnt(6)" ::: "memory");
            else if (kt2 == 30) asm volatile("s_waitcnt vmcnt(3)" ::: "memory");
            else                asm volatile("s_waitcnt vmcnt(0)" ::: "memory");
            __builtin_amdgcn_s_barrier();
            __builtin_amdgcn_sched_barrier(0);
            if (kt2 < 29) STAGE((kt2 + 3) & 3, kt2 + 3);
            __builtin_amdgcn_s_setprio(1);
            MFMA_PHASE(kt2 & 3);
            __builtin_amdgcn_s_setprio(0);
        }

        const int q0 = mt * 64 + wq * 32;
#pragma unroll
        for (int i = 0; i < 2; ++i)
#pragma unroll
            for (int j = 0; j < 2; ++j)
#pragma unroll
                for (int r = 0; r < 4; ++r)
                    out[((size_t)b * SQ_ + q0 + i * 16 + hi * 4 + r) * D_ + (wd * 2 + j) * 16 + ql]
                        = acc[i][j][r];
#undef STAGE
#undef MFMA_PHASE
    }
}

// ---------------------------------------------------------------------------
extern "C" void kernel_launch(void* const* d_in, const int* in_sizes, int n_in,
                              void* d_out, int out_size, void* d_ws, size_t ws_size,
                              hipStream_t stream) {
    const float* Q = (const float*)d_in[0];
    const float* K = (const float*)d_in[1];
    const float* V = (const float*)d_in[2];
    float* out = (float*)d_out;

    _Float16* Qf = (_Float16*)d_ws;                       // 4 MB
    _Float16* Kf = Qf + (size_t)B_ * QK_BSTRIDE;          // 4 MB
    _Float16* Kend = Kf + (size_t)B_ * QK_BSTRIDE;
    _Float16* Vf = Kend;                                  // 4 MB
    _Float16* Pf = Vf + (size_t)B_ * VF_BSTRIDE;          // 64 MB (ends at 76 MB)
    unsigned* bar = (unsigned*)((char*)d_ws + (size_t)128 * 1024 * 1024);

    hipMemsetAsync(bar, 0, 256, stream);                  // barrier state per call
    mega<<<GRID, 512, 0, stream>>>(Q, K, V, Qf, Kf, Vf, Pf, bar, out);
}

// Round 12
// 69.633 us; speedup vs baseline: 1.5642x; 1.5642x over previous
//
#include <hip/hip_runtime.h>
#include <hip/hip_bf16.h>

#define B_   8
#define SQ_  2048
#define SK_  2048
#define D_   128

typedef __attribute__((ext_vector_type(8))) _Float16 f16x8;
typedef __attribute__((ext_vector_type(4))) _Float16 f16x4;
typedef __attribute__((ext_vector_type(4))) float    f32x4;

// Fragment-major layouts (f16), lane l, hi = l>>4, ql = l&15:
//  Qf[b][qt:128][ks:4][l][8] : elem (q = qt*16+ql, d = ks*32+hi*8+j)  PRE-SCALED log2e/8
//  Kf[b][kt:128][ks:4][l][8] : elem (k = kt*16+ql, d = ks*32+hi*8+j)  PRE-SCALED 1/16
//  Vf[b][kt:64][dt:8][l][8]  : elem (k = kt*32+hi*8+j, d = dt*16+ql)   (B-frag for PV)
//  Pf[b][qtl][kt:64][l][8]   : elem (q = qtl*16+ql, k = kt*32+hi*8+j)  (A-frag for PV)
// => S(mfma) = (Q.K) * log2e/128, so exp(QK/128) = exp2(S): one v_exp_f32.
#define QK_BSTRIDE (128 * 4 * 64 * 8)   // 262144 elems per batch
#define VF_BSTRIDE (64 * 8 * 64 * 8)    // 262144 elems per batch

__device__ __forceinline__ void dma16(const void* g, void* l) {
    __builtin_amdgcn_global_load_lds(
        (const __attribute__((address_space(1))) unsigned int*)g,
        (__attribute__((address_space(3))) unsigned int*)l, 16, 0, 0);
}

__device__ __forceinline__ float fast_exp2(float x) {
#if __has_builtin(__builtin_amdgcn_exp2f)
    return __builtin_amdgcn_exp2f(x);
#else
    return __expf(x * 0.6931471805599453f);
#endif
}

// ---------------------------------------------------------------------------
// prep: blocks 0..511   -> Q,K fp32 -> fragment-major f16 (pre-scaled),
//                          fully-coalesced nt reads via LDS repack
//       blocks 512..767 -> V fp32 -> PV-B-fragment-major f16
// ---------------------------------------------------------------------------
__global__ __launch_bounds__(256)
void prep(const float* __restrict__ Q, const float* __restrict__ K,
          const float* __restrict__ V,
          _Float16* __restrict__ Qf, _Float16* __restrict__ Kf,
          _Float16* __restrict__ Vf) {
    __shared__ _Float16 T[64][136];
    const int bid = blockIdx.x;
    const int t   = threadIdx.x;
    if (bid < 512) {
        const int tens = bid >> 8;            // 0 = Q, 1 = K
        const float* src = tens ? K : Q;
        _Float16*    dst = tens ? Kf : Qf;
        const float  sc  = tens ? 0.0625f : 0.18033688f;  // 1/16, log2e/8
        const int b  = (bid >> 5) & 7;
        const int rb = bid & 31;              // 64-row block
        const int row = t >> 2, c0 = (t & 3) * 32;
        const float* srow = src + ((size_t)b * 2048 + rb * 64 + row) * 128 + c0;
#pragma unroll
        for (int u = 0; u < 32; u += 4) {
            f32x4 v = __builtin_nontemporal_load((const f32x4*)(srow + u));
            f16x4 h;
            h[0] = (_Float16)(v[0] * sc); h[1] = (_Float16)(v[1] * sc);
            h[2] = (_Float16)(v[2] * sc); h[3] = (_Float16)(v[3] * sc);
            *(f16x4*)&T[row][c0 + u] = h;
        }
        __syncthreads();
        // 1024 f16x8 chunks in fragment order, contiguous global stores
#pragma unroll
        for (int u = 0; u < 4; ++u) {
            int c  = u * 256 + t;
            int l  = c & 63;
            int ks = (c >> 6) & 3;
            int qt = c >> 8;                  // 0..3
            int hi = l >> 4, ql = l & 15;
            f16x8 r = *(const f16x8*)&T[qt * 16 + ql][ks * 32 + hi * 8];
            *(f16x8*)(dst + ((((size_t)b * 128 + rb * 4 + qt) * 4 + ks) * 64 + l) * 8) = r;
        }
    } else {
        const int vb = bid - 512;             // 0..255
        const int b  = vb >> 5;
        const int kb = vb & 31;
        const int row = t >> 2, c0 = (t & 3) * 32;
        const float* src = V + ((size_t)b * SK_ + kb * 64 + row) * D_ + c0;
#pragma unroll
        for (int u = 0; u < 8; ++u) {
            f32x4 v = __builtin_nontemporal_load((const f32x4*)(src + u * 4));
            f16x4 h;
            h[0] = (_Float16)v[0]; h[1] = (_Float16)v[1];
            h[2] = (_Float16)v[2]; h[3] = (_Float16)v[3];
            *(f16x4*)&T[row][c0 + u * 4] = h;
        }
        __syncthreads();
#pragma unroll
        for (int u = 0; u < 4; ++u) {
            int s   = u * 256 + t;            // 0..1023
            int l   = s & 63;
            int dt  = (s >> 6) & 7;
            int ktl = s >> 9;                 // 0..1
            int hi  = l >> 4, ql = l & 15;
            f16x8 r;
#pragma unroll
            for (int j = 0; j < 8; ++j) r[j] = T[ktl * 32 + hi * 8 + j][dt * 16 + ql];
            *(f16x8*)(Vf + (((size_t)b * 64 + kb * 2 + ktl) * 8 + dt) * 512 + (size_t)l * 8) = r;
        }
    }
}

// ---------------------------------------------------------------------------
// Phase 1: P_b[q][k] = exp2(S_b) / sum_b exp2(S_b), written for ALL 8
// batches in PV-A-fragment-major layout. grid (nq/64)*32, block 512.
// Pf stores are NONTEMPORAL: written once, consumed on other XCDs — keep
// them out of this XCD's L2 so the 32x-reused Qf/Kf tiles stay resident.
// ---------------------------------------------------------------------------
__global__ __launch_bounds__(512, 4)
void zred(const _Float16* __restrict__ Qf, const _Float16* __restrict__ Kf,
          _Float16* __restrict__ Pf, int nqt, int qoff16) {
    __shared__ __attribute__((aligned(16))) _Float16 E[8][64][64];  // 64 KB
    const int bid   = blockIdx.x;
    const int qtile = bid >> 5;          // local to chunk
    const int ktile = bid & 31;
    const int b  = threadIdx.x >> 6;
    const int l  = threadIdx.x & 63;
    const int hi = l >> 4, ql = l & 15;

    const _Float16* Qb = Qf + (size_t)b * QK_BSTRIDE;
    const _Float16* Kb = Kf + (size_t)b * QK_BSTRIDE;

    // swapped S^T = mfma(K, Q): lane holds k = kk*16+hi*4+r, q = qq*16+ql
    f32x4 s[4][4] = {};
    __builtin_amdgcn_s_setprio(1);
#pragma unroll
    for (int ks = 0; ks < 4; ++ks) {
        f16x8 kf[4];
#pragma unroll
        for (int kk = 0; kk < 4; ++kk)
            kf[kk] = *(const f16x8*)(Kb + ((((size_t)ktile * 4 + kk) * 4 + ks) * 64 + l) * 8);
#pragma unroll
        for (int qq = 0; qq < 4; ++qq) {
            f16x8 qv = *(const f16x8*)(Qb + ((((size_t)(qoff16 + qtile * 4 + qq)) * 4 + ks) * 64 + l) * 8);
#pragma unroll
            for (int kk = 0; kk < 4; ++kk)
                s[kk][qq] = __builtin_amdgcn_mfma_f32_16x16x32_f16(kf[kk], qv, s[kk][qq], 0, 0, 0);
        }
    }
    __builtin_amdgcn_s_setprio(0);

    // E[b][q][k] = exp2(S), 16B-granule XOR swizzle on k-group
    f16x4* E4 = (f16x4*)&E[0][0][0];
#pragma unroll
    for (int kk = 0; kk < 4; ++kk)
#pragma unroll
        for (int qq = 0; qq < 4; ++qq) {
            f16x4 e;
#pragma unroll
            for (int r = 0; r < 4; ++r)
                e[r] = (_Float16)fast_exp2(s[kk][qq][r]);
            int q = qq * 16 + ql;
            int k = kk * 16 + hi * 4;
            int g16 = ((b * 64 + q) << 3) + ((k >> 3) ^ (q & 7));
            E4[g16 * 2 + ((k >> 2) & 1)] = e;
        }
    __syncthreads();

    // thread -> PV-A-frag slot: (ktl, qq2, lane)
    const int t    = threadIdx.x;
    const int ktl  = t >> 8;             // 0..1
    const int qq2  = (t >> 6) & 3;       // 0..3
    const int l2   = t & 63;
    const int hi2  = l2 >> 4, ql2 = l2 & 15;
    const int q_loc  = qq2 * 16 + ql2;
    const int k0_loc = ktl * 32 + hi2 * 8;
    const f16x8* E8  = (const f16x8*)&E[0][0][0];
    const int eidx   = (q_loc << 3) + ((k0_loc >> 3) ^ (q_loc & 7));

    // pass 1: z = sum_b e_b
    f16x8 z = E8[eidx];
#pragma unroll
    for (int bb = 1; bb < 8; ++bb) z = z + E8[bb * 512 + eidx];
    float inv[8];
#pragma unroll
    for (int j = 0; j < 8; ++j) inv[j] = __builtin_amdgcn_rcpf((float)z[j]);

    // pass 2: P_b = e_b * inv, coalesced nontemporal f16x8 store per batch
    const size_t pbase = (((size_t)(qtile * 4 + qq2)) * 64 + (ktile * 2 + ktl)) * 512 + (size_t)l2 * 8;
#pragma unroll
    for (int bb = 0; bb < 8; ++bb) {
        f16x8 e = E8[bb * 512 + eidx];
        f16x8 p;
#pragma unroll
        for (int j = 0; j < 8; ++j) p[j] = (_Float16)((float)e[j] * inv[j]);
        __builtin_nontemporal_store(p, (f16x8*)(Pf + (size_t)bb * nqt * 32768 + pbase));
    }
}

// ---------------------------------------------------------------------------
// Phase 2: O_b = P_b @ V_b — staged GEMM, global_load_lds QUAD-buffer,
// prefetch distance 3, counted vmcnt, SINGLE barrier per iteration.
// Overwrite safety: STAGE(it+3) -> buf[(it-1)&3], whose reads were consumed
// by MFMA(it-1) before every wave reached barrier_it (program order + lgkm).
// grid (nq/64)*8, block 512. Block = (b, 64q); wave = 32q x 32d quadrant.
// ---------------------------------------------------------------------------
__global__ __launch_bounds__(512)
void av(const _Float16* __restrict__ Pf, const _Float16* __restrict__ Vf,
        float* __restrict__ out, int nqt, int qoff) {
    __shared__ __attribute__((aligned(16))) _Float16 lds[4 * 12288];  // 4 x 24KB

    const int bid = blockIdx.x;
    const int b   = bid & 7;             // batch -> XCD pinned (V_b L2-resident)
    const int mt  = bid >> 3;            // 64-q M-tile (chunk-local)
    const int w   = threadIdx.x >> 6;
    const int l   = threadIdx.x & 63;
    const int wq  = w >> 2;              // 0..1
    const int wd  = w & 3;               // 0..3
    const int hi  = l >> 4, ql = l & 15;

    const _Float16* Pb = Pf + (size_t)b * nqt * 32768;
    const _Float16* Vb = Vf + (size_t)b * VF_BSTRIDE;

#define STAGE(bufi, kt2) do {                                                  \
    _Float16* dst0 = (_Float16*)lds + (size_t)(bufi) * 12288;                  \
    _Pragma("unroll")                                                          \
    for (int u = 0; u < 3; ++u) {                                              \
        int c = w * 3 + u;                                                     \
        const _Float16* srcp;                                                  \
        if (c < 8)                                                             \
            srcp = Pb + (((size_t)(mt * 4 + (c >> 1))) * 64 + ((kt2) * 2 + (c & 1))) * 512 + (size_t)l * 8; \
        else {                                                                 \
            int cv = c - 8;                                                    \
            srcp = Vb + (((size_t)((kt2) * 2 + (cv >> 3))) * 8 + (cv & 7)) * 512 + (size_t)l * 8; \
        }                                                                      \
        dma16(srcp, dst0 + c * 512);                                           \
    }                                                                          \
} while (0)

#define MFMA_PHASE(bufi) do {                                                  \
    const _Float16* Bf = (const _Float16*)lds + (size_t)(bufi) * 12288;        \
    _Pragma("unroll")                                                          \
    for (int ktl = 0; ktl < 2; ++ktl) {                                        \
        f16x8 pfr[2], vfr[2];                                                  \
        _Pragma("unroll")                                                      \
        for (int i = 0; i < 2; ++i)                                            \
            pfr[i] = *(const f16x8*)(Bf + ((wq * 2 + i) * 2 + ktl) * 512 + l * 8); \
        _Pragma("unroll")                                                      \
        for (int j = 0; j < 2; ++j)                                            \
            vfr[j] = *(const f16x8*)(Bf + 4096 + (ktl * 8 + wd * 2 + j) * 512 + l * 8); \
        _Pragma("unroll")                                                      \
        for (int i = 0; i < 2; ++i)                                            \
            _Pragma("unroll")                                                  \
            for (int j = 0; j < 2; ++j)                                        \
                acc[i][j] = __builtin_amdgcn_mfma_f32_16x16x32_f16(pfr[i], vfr[j], acc[i][j], 0, 0, 0); \
    }                                                                          \
} while (0)

    f32x4 acc[2][2] = {};
    STAGE(0, 0);
    STAGE(1, 1);
    STAGE(2, 2);
    for (int kt2 = 0; kt2 < 32; ++kt2) {
        // stage[kt2] is the oldest in-flight group; <=2 newer groups (6 loads)
        if (kt2 <= 29)      asm volatile("s_waitcnt vmcnt(6)" ::: "memory");
        else if (kt2 == 30) asm volatile("s_waitcnt vmcnt(3)" ::: "memory");
        else                asm volatile("s_waitcnt vmcnt(0)" ::: "memory");
        __builtin_amdgcn_s_barrier();          // all waves' stage[kt2] landed
        __builtin_amdgcn_sched_barrier(0);     // no ds_read hoisting above
        if (kt2 < 29) STAGE((kt2 + 3) & 3, kt2 + 3);
        __builtin_amdgcn_s_setprio(1);
        MFMA_PHASE(kt2 & 3);
        __builtin_amdgcn_s_setprio(0);
    }

    // D-layout: q = +hi*4+r, d = +ql ; each output element written once.
    // Nontemporal: out is never re-read — don't pollute L2 with it.
    const int q0 = qoff + mt * 64 + wq * 32;
#pragma unroll
    for (int i = 0; i < 2; ++i)
#pragma unroll
        for (int j = 0; j < 2; ++j)
#pragma unroll
            for (int r = 0; r < 4; ++r)
                __builtin_nontemporal_store(acc[i][j][r],
                    &out[((size_t)b * SQ_ + q0 + i * 16 + hi * 4 + r) * D_ + (wd * 2 + j) * 16 + ql]);
#undef STAGE
#undef MFMA_PHASE
}

// ---------------------------------------------------------------------------
extern "C" void kernel_launch(void* const* d_in, const int* in_sizes, int n_in,
                              void* d_out, int out_size, void* d_ws, size_t ws_size,
                              hipStream_t stream) {
    const float* Q = (const float*)d_in[0];
    const float* K = (const float*)d_in[1];
    const float* V = (const float*)d_in[2];
    float* out = (float*)d_out;

    _Float16* Qf = (_Float16*)d_ws;                       // 4 MB
    _Float16* Kf = Qf + (size_t)B_ * QK_BSTRIDE;          // 4 MB
    _Float16* Vf = Kf + (size_t)B_ * QK_BSTRIDE;          // 4 MB
    _Float16* Pf = Vf + (size_t)B_ * VF_BSTRIDE;          // up to 64 MB

    // fit P-chunk (nq q-rows): nq * 8b * 2048k * 2B = nq * 32KB
    size_t used  = (size_t)(12 * 1024 * 1024);
    size_t avail = ws_size > used ? (ws_size - used) / 2 : 0;   // f16 elems
    int nq = 2048;
    while (nq > 64 && (size_t)nq * 16384 > avail) nq >>= 1;
    int nchunks = 2048 / nq;
    int nqt = nq / 16;

    prep<<<768, 256, 0, stream>>>(Q, K, V, Qf, Kf, Vf);

    for (int ci = 0; ci < nchunks; ++ci) {
        int qoff = ci * nq;
        zred<<<(nq / 64) * 32, 512, 0, stream>>>(Qf, Kf, Pf, nqt, qoff >> 4);
        av<<<(nq / 64) * 8, 512, 0, stream>>>(Pf, Vf, out, nqt, qoff);
    }
}

// Round 13
// 56.337 us; speedup vs baseline: 1.9333x; 1.2360x over previous
//
#include <hip/hip_runtime.h>
#include <hip/hip_bf16.h>

#define B_   8
#define SQ_  2048
#define SK_  2048
#define D_   128

typedef __attribute__((ext_vector_type(8))) _Float16 f16x8;
typedef __attribute__((ext_vector_type(4))) _Float16 f16x4;
typedef __attribute__((ext_vector_type(4))) float    f32x4;

// Fragment-major layouts (f16), lane l, hi = l>>4, ql = l&15:
//  Qf[b][qt:128][ks:4][l][8] : elem (q = qt*16+ql, d = ks*32+hi*8+j)  PRE-SCALED log2e/8
//  Kf[b][kt:128][ks:4][l][8] : elem (k = kt*16+ql, d = ks*32+hi*8+j)  PRE-SCALED 1/16
//  Vf[b][kt:64][dt:8][l][8]  : elem (k = kt*32+hi*8+j, d = dt*16+ql)   (B-frag for PV)
//  Pf[b][qtl][kt:64][l][8]   : elem (q = qtl*16+ql, k = kt*32+hi*8+j)  (A-frag for PV)
// => S(mfma) = (Q.K) * log2e/128, so exp(QK/128) = exp2(S): one v_exp_f32.
// NOTE (r12 lesson): Pf lives in LLC between zred and av — NO nontemporal
// hints anywhere on this path (nt pushed it to HBM, +12us).
#define QK_BSTRIDE (128 * 4 * 64 * 8)   // 262144 elems per batch
#define VF_BSTRIDE (64 * 8 * 64 * 8)    // 262144 elems per batch

__device__ __forceinline__ void dma16(const void* g, void* l) {
    __builtin_amdgcn_global_load_lds(
        (const __attribute__((address_space(1))) unsigned int*)g,
        (__attribute__((address_space(3))) unsigned int*)l, 16, 0, 0);
}

__device__ __forceinline__ float fast_exp2(float x) {
#if __has_builtin(__builtin_amdgcn_exp2f)
    return __builtin_amdgcn_exp2f(x);
#else
    return __expf(x * 0.6931471805599453f);
#endif
}

// ---------------------------------------------------------------------------
// prep: blocks 0..511   -> Q,K fp32 -> fragment-major f16 (pre-scaled),
//                          fully-coalesced reads via LDS repack
//       blocks 512..767 -> V fp32 -> PV-B-fragment-major f16
// ---------------------------------------------------------------------------
__global__ __launch_bounds__(256)
void prep(const float* __restrict__ Q, const float* __restrict__ K,
          const float* __restrict__ V,
          _Float16* __restrict__ Qf, _Float16* __restrict__ Kf,
          _Float16* __restrict__ Vf) {
    __shared__ _Float16 T[64][136];
    const int bid = blockIdx.x;
    const int t   = threadIdx.x;
    if (bid < 512) {
        const int tens = bid >> 8;            // 0 = Q, 1 = K
        const float* src = tens ? K : Q;
        _Float16*    dst = tens ? Kf : Qf;
        const float  sc  = tens ? 0.0625f : 0.18033688f;  // 1/16, log2e/8
        const int b  = (bid >> 5) & 7;
        const int rb = bid & 31;              // 64-row block
        const int row = t >> 2, c0 = (t & 3) * 32;
        const float* srow = src + ((size_t)b * 2048 + rb * 64 + row) * 128 + c0;
#pragma unroll
        for (int u = 0; u < 32; u += 4) {
            f32x4 v = *(const f32x4*)(srow + u);
            f16x4 h;
            h[0] = (_Float16)(v[0] * sc); h[1] = (_Float16)(v[1] * sc);
            h[2] = (_Float16)(v[2] * sc); h[3] = (_Float16)(v[3] * sc);
            *(f16x4*)&T[row][c0 + u] = h;
        }
        __syncthreads();
        // 1024 f16x8 chunks in fragment order, contiguous global stores
#pragma unroll
        for (int u = 0; u < 4; ++u) {
            int c  = u * 256 + t;
            int l  = c & 63;
            int ks = (c >> 6) & 3;
            int qt = c >> 8;                  // 0..3
            int hi = l >> 4, ql = l & 15;
            f16x8 r = *(const f16x8*)&T[qt * 16 + ql][ks * 32 + hi * 8];
            *(f16x8*)(dst + ((((size_t)b * 128 + rb * 4 + qt) * 4 + ks) * 64 + l) * 8) = r;
        }
    } else {
        const int vb = bid - 512;             // 0..255
        const int b  = vb >> 5;
        const int kb = vb & 31;
        const int row = t >> 2, c0 = (t & 3) * 32;
        const float* src = V + ((size_t)b * SK_ + kb * 64 + row) * D_ + c0;
#pragma unroll
        for (int u = 0; u < 8; ++u) {
            f32x4 v = *(const f32x4*)(src + u * 4);
            f16x4 h;
            h[0] = (_Float16)v[0]; h[1] = (_Float16)v[1];
            h[2] = (_Float16)v[2]; h[3] = (_Float16)v[3];
            *(f16x4*)&T[row][c0 + u * 4] = h;
        }
        __syncthreads();
#pragma unroll
        for (int u = 0; u < 4; ++u) {
            int s   = u * 256 + t;            // 0..1023
            int l   = s & 63;
            int dt  = (s >> 6) & 7;
            int ktl = s >> 9;                 // 0..1
            int hi  = l >> 4, ql = l & 15;
            f16x8 r;
#pragma unroll
            for (int j = 0; j < 8; ++j) r[j] = T[ktl * 32 + hi * 8 + j][dt * 16 + ql];
            *(f16x8*)(Vf + (((size_t)b * 64 + kb * 2 + ktl) * 8 + dt) * 512 + (size_t)l * 8) = r;
        }
    }
}

// ---------------------------------------------------------------------------
// Phase 1: P_b[q][k] = exp2(S_b) / sum_b exp2(S_b), written for ALL 8
// batches in PV-A-fragment-major layout. grid (nq/64)*32, block 512.
// ---------------------------------------------------------------------------
__global__ __launch_bounds__(512, 4)
void zred(const _Float16* __restrict__ Qf, const _Float16* __restrict__ Kf,
          _Float16* __restrict__ Pf, int nqt, int qoff16) {
    __shared__ __attribute__((aligned(16))) _Float16 E[8][64][64];  // 64 KB
    const int bid   = blockIdx.x;
    const int qtile = bid >> 5;          // local to chunk
    const int ktile = bid & 31;
    const int b  = threadIdx.x >> 6;
    const int l  = threadIdx.x & 63;
    const int hi = l >> 4, ql = l & 15;

    const _Float16* Qb = Qf + (size_t)b * QK_BSTRIDE;
    const _Float16* Kb = Kf + (size_t)b * QK_BSTRIDE;

    // swapped S^T = mfma(K, Q): lane holds k = kk*16+hi*4+r, q = qq*16+ql
    f32x4 s[4][4] = {};
    __builtin_amdgcn_s_setprio(1);
#pragma unroll
    for (int ks = 0; ks < 4; ++ks) {
        f16x8 kf[4];
#pragma unroll
        for (int kk = 0; kk < 4; ++kk)
            kf[kk] = *(const f16x8*)(Kb + ((((size_t)ktile * 4 + kk) * 4 + ks) * 64 + l) * 8);
#pragma unroll
        for (int qq = 0; qq < 4; ++qq) {
            f16x8 qv = *(const f16x8*)(Qb + ((((size_t)(qoff16 + qtile * 4 + qq)) * 4 + ks) * 64 + l) * 8);
#pragma unroll
            for (int kk = 0; kk < 4; ++kk)
                s[kk][qq] = __builtin_amdgcn_mfma_f32_16x16x32_f16(kf[kk], qv, s[kk][qq], 0, 0, 0);
        }
    }
    __builtin_amdgcn_s_setprio(0);

    // E[b][q][k] = exp2(S), 16B-granule XOR swizzle on k-group
    f16x4* E4 = (f16x4*)&E[0][0][0];
#pragma unroll
    for (int kk = 0; kk < 4; ++kk)
#pragma unroll
        for (int qq = 0; qq < 4; ++qq) {
            f16x4 e;
#pragma unroll
            for (int r = 0; r < 4; ++r)
                e[r] = (_Float16)fast_exp2(s[kk][qq][r]);
            int q = qq * 16 + ql;
            int k = kk * 16 + hi * 4;
            int g16 = ((b * 64 + q) << 3) + ((k >> 3) ^ (q & 7));
            E4[g16 * 2 + ((k >> 2) & 1)] = e;
        }
    __syncthreads();

    // thread -> PV-A-frag slot: (ktl, qq2, lane)
    const int t    = threadIdx.x;
    const int ktl  = t >> 8;             // 0..1
    const int qq2  = (t >> 6) & 3;       // 0..3
    const int l2   = t & 63;
    const int hi2  = l2 >> 4, ql2 = l2 & 15;
    const int q_loc  = qq2 * 16 + ql2;
    const int k0_loc = ktl * 32 + hi2 * 8;
    const f16x8* E8  = (const f16x8*)&E[0][0][0];
    const int eidx   = (q_loc << 3) + ((k0_loc >> 3) ^ (q_loc & 7));

    // pass 1: z = sum_b e_b
    f16x8 z = E8[eidx];
#pragma unroll
    for (int bb = 1; bb < 8; ++bb) z = z + E8[bb * 512 + eidx];
    float inv[8];
#pragma unroll
    for (int j = 0; j < 8; ++j) inv[j] = __builtin_amdgcn_rcpf((float)z[j]);

    // pass 2: P_b = e_b * inv, coalesced f16x8 store per batch
    const size_t pbase = (((size_t)(qtile * 4 + qq2)) * 64 + (ktile * 2 + ktl)) * 512 + (size_t)l2 * 8;
#pragma unroll
    for (int bb = 0; bb < 8; ++bb) {
        f16x8 e = E8[bb * 512 + eidx];
        f16x8 p;
#pragma unroll
        for (int j = 0; j < 8; ++j) p[j] = (_Float16)((float)e[j] * inv[j]);
        *(f16x8*)(Pf + (size_t)bb * nqt * 32768 + pbase) = p;
    }
}

// ---------------------------------------------------------------------------
// Phase 2: O_b = P_b @ V_b — staged GEMM, global_load_lds, K-STEP 128:
// 3 x 48KB buffers, prefetch distance 2, counted vmcnt(12), single barrier
// per 128-k iteration (16 iters: half the barrier count of K-step 64).
// Per iter: stage P 16KB + V 32KB = 48 x 1KB DMA chunks (6 per wave).
// Overwrite safety: STAGE(kt4+2) -> buf[(kt4-1)%3], whose reads were consumed
// by MFMA(kt4-1) before every wave reached barrier_kt4 (program order + lgkm).
// grid (nq/64)*8, block 512. Block = (b, 64q); wave = 32q x 32d quadrant.
// ---------------------------------------------------------------------------
__global__ __launch_bounds__(512)
void av(const _Float16* __restrict__ Pf, const _Float16* __restrict__ Vf,
        float* __restrict__ out, int nqt, int qoff) {
    __shared__ __attribute__((aligned(16))) _Float16 lds[3 * 24576];  // 3 x 48KB

    const int bid = blockIdx.x;
    const int b   = bid & 7;             // batch -> XCD pinned (V_b L2-resident)
    const int mt  = bid >> 3;            // 64-q M-tile (chunk-local)
    const int w   = threadIdx.x >> 6;
    const int l   = threadIdx.x & 63;
    const int wq  = w >> 2;              // 0..1
    const int wd  = w & 3;               // 0..3
    const int hi  = l >> 4, ql = l & 15;

    const _Float16* Pb = Pf + (size_t)b * nqt * 32768;
    const _Float16* Vb = Vf + (size_t)b * VF_BSTRIDE;

#define STAGE(bufi, kt4) do {                                                  \
    _Float16* dst0 = (_Float16*)lds + (size_t)(bufi) * 24576;                  \
    _Pragma("unroll")                                                          \
    for (int u = 0; u < 6; ++u) {                                              \
        int c = w * 6 + u;                                                     \
        const _Float16* srcp;                                                  \
        if (c < 16)                                                            \
            srcp = Pb + (((size_t)(mt * 4 + (c >> 2))) * 64 + ((kt4) * 4 + (c & 3))) * 512 + (size_t)l * 8; \
        else {                                                                 \
            int cv = c - 16;                                                   \
            srcp = Vb + (((size_t)((kt4) * 4 + (cv >> 3))) * 8 + (cv & 7)) * 512 + (size_t)l * 8; \
        }                                                                      \
        dma16(srcp, dst0 + c * 512);                                           \
    }                                                                          \
} while (0)

#define MFMA_PHASE(bufi) do {                                                  \
    const _Float16* Bf = (const _Float16*)lds + (size_t)(bufi) * 24576;        \
    _Pragma("unroll")                                                          \
    for (int ktl = 0; ktl < 4; ++ktl) {                                        \
        f16x8 pfr[2], vfr[2];                                                  \
        _Pragma("unroll")                                                      \
        for (int i = 0; i < 2; ++i)                                            \
            pfr[i] = *(const f16x8*)(Bf + ((wq * 2 + i) * 4 + ktl) * 512 + l * 8); \
        _Pragma("unroll")                                                      \
        for (int j = 0; j < 2; ++j)                                            \
            vfr[j] = *(const f16x8*)(Bf + 8192 + (ktl * 8 + wd * 2 + j) * 512 + l * 8); \
        _Pragma("unroll")                                                      \
        for (int i = 0; i < 2; ++i)                                            \
            _Pragma("unroll")                                                  \
            for (int j = 0; j < 2; ++j)                                        \
                acc[i][j] = __builtin_amdgcn_mfma_f32_16x16x32_f16(pfr[i], vfr[j], acc[i][j], 0, 0, 0); \
    }                                                                          \
} while (0)

    f32x4 acc[2][2] = {};
    STAGE(0, 0);
    STAGE(1, 1);
    for (int kt4 = 0; kt4 < 16; ++kt4) {
        // oldest in-flight stage = kt4; at most 2 newer stages (12 chunks/wave)
        if (kt4 <= 13)      asm volatile("s_waitcnt vmcnt(12)" ::: "memory");
        else if (kt4 == 14) asm volatile("s_waitcnt vmcnt(6)" ::: "memory");
        else                asm volatile("s_waitcnt vmcnt(0)" ::: "memory");
        __builtin_amdgcn_s_barrier();          // all waves' stage[kt4] landed
        __builtin_amdgcn_sched_barrier(0);     // no ds_read hoisting above
        if (kt4 < 14) STAGE((kt4 + 2) % 3, kt4 + 2);
        __builtin_amdgcn_s_setprio(1);
        MFMA_PHASE(kt4 % 3);
        __builtin_amdgcn_s_setprio(0);
    }

    // D-layout: q = +hi*4+r, d = +ql ; each output element written once
    const int q0 = qoff + mt * 64 + wq * 32;
#pragma unroll
    for (int i = 0; i < 2; ++i)
#pragma unroll
        for (int j = 0; j < 2; ++j)
#pragma unroll
            for (int r = 0; r < 4; ++r)
                out[((size_t)b * SQ_ + q0 + i * 16 + hi * 4 + r) * D_ + (wd * 2 + j) * 16 + ql]
                    = acc[i][j][r];
#undef STAGE
#undef MFMA_PHASE
}

// ---------------------------------------------------------------------------
extern "C" void kernel_launch(void* const* d_in, const int* in_sizes, int n_in,
                              void* d_out, int out_size, void* d_ws, size_t ws_size,
                              hipStream_t stream) {
    const float* Q = (const float*)d_in[0];
    const float* K = (const float*)d_in[1];
    const float* V = (const float*)d_in[2];
    float* out = (float*)d_out;

    _Float16* Qf = (_Float16*)d_ws;                       // 4 MB
    _Float16* Kf = Qf + (size_t)B_ * QK_BSTRIDE;          // 4 MB
    _Float16* Vf = Kf + (size_t)B_ * QK_BSTRIDE;          // 4 MB
    _Float16* Pf = Vf + (size_t)B_ * VF_BSTRIDE;          // up to 64 MB

    // fit P-chunk (nq q-rows): nq * 8b * 2048k * 2B = nq * 32KB
    size_t used  = (size_t)(12 * 1024 * 1024);
    size_t avail = ws_size > used ? (ws_size - used) / 2 : 0;   // f16 elems
    int nq = 2048;
    while (nq > 64 && (size_t)nq * 16384 > avail) nq >>= 1;
    int nchunks = 2048 / nq;
    int nqt = nq / 16;

    prep<<<768, 256, 0, stream>>>(Q, K, V, Qf, Kf, Vf);

    for (int ci = 0; ci < nchunks; ++ci) {
        int qoff = ci * nq;
        zred<<<(nq / 64) * 32, 512, 0, stream>>>(Qf, Kf, Pf, nqt, qoff >> 4);
        av<<<(nq / 64) * 8, 512, 0, stream>>>(Pf, Vf, out, nqt, qoff);
    }
}